// Round 1
// 1797.668 us; speedup vs baseline: 1.0812x; 1.0812x over previous
//
#include <hip/hip_runtime.h>

// Problem constants (SpatialEncoding_46943992545790)
#define T_STEPS 4
#define NN 50000
#define EE 800000
#define DD 256
#define VOCAB 64000
#define NB ((NN + 255) / 256)   // 196 scan blocks

typedef __attribute__((ext_vector_type(8))) short short8;
typedef __attribute__((ext_vector_type(4))) float floatx4;

// ---------------------------------------------------------------- bf16 helpers
__device__ __forceinline__ unsigned short f2bf(float f) {
    unsigned u = __float_as_uint(f);
    return (unsigned short)((u + 0x7FFFu + ((u >> 16) & 1u)) >> 16);  // RNE
}
__device__ __forceinline__ float bf2f(unsigned short s) {
    return __uint_as_float(((unsigned)s) << 16);
}

__device__ __forceinline__ void async16(const unsigned short* g, unsigned short* l) {
    __builtin_amdgcn_global_load_lds(
        (const __attribute__((address_space(1))) void*)g,
        (__attribute__((address_space(3))) void*)l, 16, 0, 0);
}

// ---------------------------------------------------------------- init
__global__ __launch_bounds__(256) void init_deg_cnt(float* __restrict__ deg,
                                                    int* __restrict__ cnt, int n) {
    int i = blockIdx.x * 256 + threadIdx.x;
    if (i < n) { deg[i] = 1.0f; cnt[i] = 0; }   // self-loop weight 1
}

// ------------------------------------------------- edge pass: deg + counts
__global__ __launch_bounds__(256) void edge_deg_cnt(const int* __restrict__ col,
                                                    const float* __restrict__ w,
                                                    float* __restrict__ deg,
                                                    int* __restrict__ cnt, int e) {
    int i = blockIdx.x * 256 + threadIdx.x;
    if (i < e) {
        int c = col[i];
        atomicAdd(&deg[c], w[i]);
        atomicAdd(&cnt[c], 1);
    }
}

// ---------------------------------------------------------------- dinv
__global__ __launch_bounds__(256) void compute_dinv(const float* __restrict__ deg,
                                                    float* __restrict__ dinv, int n) {
    int i = blockIdx.x * 256 + threadIdx.x;
    if (i < n) {
        float d = deg[i];
        dinv[i] = d > 0.0f ? rsqrtf(d) : 0.0f;
    }
}

// --------------------------------------------------- parallel scan, pass 1
__global__ __launch_bounds__(256) void block_sums(const int* __restrict__ cnt,
                                                  int* __restrict__ bsum, int n) {
    __shared__ int sm[256];
    int i = blockIdx.x * 256 + threadIdx.x;
    sm[threadIdx.x] = (i < n) ? cnt[i] : 0;
    __syncthreads();
    for (int s = 128; s > 0; s >>= 1) {
        if ((int)threadIdx.x < s) sm[threadIdx.x] += sm[threadIdx.x + s];
        __syncthreads();
    }
    if (threadIdx.x == 0) bsum[blockIdx.x] = sm[0];
}

// --------------------------------------------------- parallel scan, pass 2
__global__ __launch_bounds__(256) void scan_bsum(const int* __restrict__ bsum,
                                                 int* __restrict__ boff, int nb) {
    __shared__ int sm[256];
    int v = ((int)threadIdx.x < nb) ? bsum[threadIdx.x] : 0;
    sm[threadIdx.x] = v;
    __syncthreads();
    for (int o = 1; o < 256; o <<= 1) {
        int t = (threadIdx.x >= (unsigned)o) ? sm[threadIdx.x - o] : 0;
        __syncthreads();
        sm[threadIdx.x] += t;
        __syncthreads();
    }
    if ((int)threadIdx.x < nb) boff[threadIdx.x] = sm[threadIdx.x] - v;
}

// --------------------------------------------------- parallel scan, pass 3
__global__ __launch_bounds__(256) void scan_final(const int* __restrict__ cnt,
                                                  const int* __restrict__ boff,
                                                  int* __restrict__ colptr,
                                                  int* __restrict__ next, int n, int e) {
    __shared__ int sm[256];
    int i = blockIdx.x * 256 + threadIdx.x;
    int v = (i < n) ? cnt[i] : 0;
    sm[threadIdx.x] = v;
    __syncthreads();
    for (int o = 1; o < 256; o <<= 1) {
        int t = (threadIdx.x >= (unsigned)o) ? sm[threadIdx.x - o] : 0;
        __syncthreads();
        sm[threadIdx.x] += t;
        __syncthreads();
    }
    int excl = sm[threadIdx.x] - v + boff[blockIdx.x];
    if (i < n) { colptr[i] = excl; next[i] = excl; }
    if (i == 0) colptr[n] = e;   // every edge's col is in [0,n)
}

// --------------------------------------------- fill CSR (sorted by col)
__global__ __launch_bounds__(256) void fill_csr(const int* __restrict__ row,
                                                const int* __restrict__ col,
                                                const float* __restrict__ w,
                                                const float* __restrict__ dinv,
                                                int* __restrict__ next,
                                                int* __restrict__ srow,
                                                float* __restrict__ snorm, int e) {
    int i = blockIdx.x * 256 + threadIdx.x;
    if (i < e) {
        int r = row[i], c = col[i];
        int p = atomicAdd(&next[c], 1);
        srow[p] = r;
        snorm[p] = dinv[r] * w[i] * dinv[c];
    }
}

// --------------------------------- s1 = A·1  (row sums of normalized adjacency)
__global__ __launch_bounds__(256) void s1_kernel(const int* __restrict__ colptr,
                                                 const float* __restrict__ snorm,
                                                 const float* __restrict__ dinv,
                                                 float* __restrict__ s1, int n) {
    int c = blockIdx.x * 256 + threadIdx.x;
    if (c < n) {
        float di = dinv[c];
        float s = di * di;                 // self loop
        int p1 = colptr[c + 1];
        for (int p = colptr[c]; p < p1; ++p) s += snorm[p];
        s1[c] = s;
    }
}

// --------------------------------- s2 = A·s1
__global__ __launch_bounds__(256) void s2_kernel(const int* __restrict__ colptr,
                                                 const int* __restrict__ srow,
                                                 const float* __restrict__ snorm,
                                                 const float* __restrict__ dinv,
                                                 const float* __restrict__ s1,
                                                 float* __restrict__ s2, int n) {
    int c = blockIdx.x * 256 + threadIdx.x;
    if (c < n) {
        float di = dinv[c];
        float s = di * di * s1[c];         // self loop
        int p1 = colptr[c + 1];
        for (int p = colptr[c]; p < p1; ++p) s += snorm[p] * s1[srow[p]];
        s2[c] = s;
    }
}

// --------------------------------- fp32 256x256 matmul: C = A @ B (once/launch)
__global__ __launch_bounds__(256) void matmul256(const float* __restrict__ A,
                                                 const float* __restrict__ B,
                                                 float* __restrict__ C) {
    __shared__ float arow[256];
    int i = blockIdx.x, j = threadIdx.x;
    arow[j] = A[i * 256 + j];
    __syncthreads();
    float acc = 0.f;
#pragma unroll 8
    for (int k = 0; k < 256; ++k) acc += arow[k] * B[k * 256 + j];
    C[i * 256 + j] = acc;
}

// --------------------------------- fp32 matvec: y = x @ W  (1 block, once/launch)
__global__ __launch_bounds__(256) void matvec256(const float* __restrict__ x,
                                                 const float* __restrict__ W,
                                                 float* __restrict__ y) {
    __shared__ float xs[256];
    int j = threadIdx.x;
    xs[j] = x[j];
    __syncthreads();
    float acc = 0.f;
#pragma unroll 8
    for (int k = 0; k < 256; ++k) acc += xs[k] * W[k * 256 + j];
    y[j] = acc;
}

// --------------------------------- Wc[k][n] fp32 -> wt[n][k] bf16 (transposed)
__global__ __launch_bounds__(256) void convert_wc(const float* __restrict__ Wc,
                                                  unsigned short* __restrict__ wt) {
    int n = blockIdx.x;          // 0..255
    int k = threadIdx.x;         // 0..255
    wt[n * 256 + k] = f2bf(Wc[k * 256 + n]);
}

// --------------------------------- emb fp32 -> bf16 (once per launch)
__global__ __launch_bounds__(256) void convert_emb(const float* __restrict__ emb,
                                                   unsigned short* __restrict__ ebf,
                                                   int total4) {
    int t = blockIdx.x * 256 + threadIdx.x;
    if (t < total4) {
        float4 v = ((const float4*)emb)[t];
        ushort4 o;
        o.x = f2bf(v.x); o.y = f2bf(v.y); o.z = f2bf(v.z); o.w = f2bf(v.w);
        ((ushort4*)ebf)[t] = o;
    }
}

// ------------------------------------------------------- bf16 MFMA GEMM + gather
// h2[M,256](bf16) = ebf[ids[M],256](bf16) @ W, with wt = W^T (bf16, [n][k]).
// A-operand rows are gathered through ids via per-lane global_load_lds source
// addresses (LDS dest stays linear). BM=128, BN=128, BK=32, 4 waves,
// wave = 64x64 via 4x4 grid of 16x16x32 MFMA tiles.
__global__ __launch_bounds__(256) void mfma_gemm(const int* __restrict__ ids,
                                                 const unsigned short* __restrict__ ebf,
                                                 const unsigned short* __restrict__ wt,
                                                 unsigned short* __restrict__ h2,
                                                 int M) {
    __shared__ __align__(16) unsigned short As[128 * 32];
    __shared__ __align__(16) unsigned short Bs[128 * 32];

    int tid = threadIdx.x;
    int lane = tid & 63;
    int wave = tid >> 6;
    int row0 = blockIdx.y * 128;
    int col0 = blockIdx.x * 128;
    int wm = (wave & 1) * 64;
    int wn = (wave >> 1) * 64;
    int quad = lane >> 4;
    int cl = lane & 15;

    // staging decomposition (constant across K-iters): idx = s*256 + tid
    int idx0 = tid, idx1 = 256 + tid;
    int c0 = idx0 >> 7, m0 = idx0 & 127;
    int c1 = idx1 >> 7;                 // m1 == m0 (same row, different k-chunk)
    int gr0 = row0 + m0; if (gr0 >= M) gr0 = M - 1;
    int id0 = ids[gr0];                 // embedding gather index
    const unsigned short* srcA0 = ebf + (size_t)id0 * 256 + c0 * 8;
    const unsigned short* srcA1 = ebf + (size_t)id0 * 256 + c1 * 8;
    const unsigned short* srcB0 = wt + (size_t)(col0 + m0) * 256 + c0 * 8;
    const unsigned short* srcB1 = wt + (size_t)(col0 + m0) * 256 + c1 * 8;
    unsigned short* dstA0 = As + idx0 * 8;
    unsigned short* dstA1 = As + idx1 * 8;
    unsigned short* dstB0 = Bs + idx0 * 8;
    unsigned short* dstB1 = Bs + idx1 * 8;

    floatx4 acc[4][4] = {};

    for (int k0 = 0; k0 < 256; k0 += 32) {
        if (k0) __syncthreads();          // protect LDS from prior reads
        async16(srcA0 + k0, dstA0);
        async16(srcA1 + k0, dstA1);
        async16(srcB0 + k0, dstB0);
        async16(srcB1 + k0, dstB1);
        __syncthreads();                  // drains vmcnt before barrier

        short8 af[4], bfr[4];
#pragma unroll
        for (int i = 0; i < 4; ++i)
            af[i] = *(const short8*)&As[(quad * 128 + wm + i * 16 + cl) * 8];
#pragma unroll
        for (int j = 0; j < 4; ++j)
            bfr[j] = *(const short8*)&Bs[(quad * 128 + wn + j * 16 + cl) * 8];
#pragma unroll
        for (int i = 0; i < 4; ++i)
#pragma unroll
            for (int j = 0; j < 4; ++j)
                acc[i][j] = __builtin_amdgcn_mfma_f32_16x16x32_bf16(
                    af[i], bfr[j], acc[i][j], 0, 0, 0);
    }

    // epilogue: D[row=quad*4+reg][col=lane&15] per 16x16 tile
#pragma unroll
    for (int i = 0; i < 4; ++i) {
#pragma unroll
        for (int r = 0; r < 4; ++r) {
            int gr = row0 + wm + i * 16 + quad * 4 + r;
            if (gr < M) {
                size_t base = (size_t)gr * 256 + col0 + wn + cl;
#pragma unroll
                for (int j = 0; j < 4; ++j)
                    h2[base + j * 16] = f2bf(acc[i][j][r]);
            }
        }
    }
}

// ------------------------------------------- CSR aggregate (bf16 gather)
// Intermediate (dstb != 0): dst[c,:] = sum_e snorm[e]*h2[srow[e],:] + dinv[c]^2*h2[c,:]
// Final (dstb == 0):        dst[c,:] = agg + s2[c]*v1 + s1[c]*v2 + b3     (fp32)
__global__ __launch_bounds__(256) void agg_kernel(const unsigned short* __restrict__ h2,
                                                  const int* __restrict__ colptr,
                                                  const int* __restrict__ srow,
                                                  const float* __restrict__ snorm,
                                                  const float* __restrict__ dinv,
                                                  const float* __restrict__ s1,
                                                  const float* __restrict__ s2,
                                                  const float* __restrict__ v1,
                                                  const float* __restrict__ v2,
                                                  const float* __restrict__ b3,
                                                  float* __restrict__ dstf,
                                                  unsigned short* __restrict__ dstb,
                                                  int n) {
    int wave = threadIdx.x >> 6;
    int lane = threadIdx.x & 63;
    int c = blockIdx.x * 4 + wave;
    if (c >= n) return;
    int p0 = colptr[c];
    int p1 = colptr[c + 1];
    float di = dinv[c];
    float self = di * di;

    const ushort4* h4 = (const ushort4*)h2;   // 4 bf16 = 8 B per lane
    int cbase = c * 64 + lane;

    ushort4 sv = h4[cbase];
    float ax = self * bf2f(sv.x), ay = self * bf2f(sv.y);
    float az = self * bf2f(sv.z), aw = self * bf2f(sv.w);
    float bx = 0.f, by = 0.f, bz = 0.f, bw = 0.f;

    int j = p0;
    for (; j + 1 < p1; j += 2) {
        int r0 = srow[j];
        int r1 = srow[j + 1];
        float w0 = snorm[j];
        float w1 = snorm[j + 1];
        ushort4 v0 = h4[(size_t)r0 * 64 + lane];
        ushort4 v1q = h4[(size_t)r1 * 64 + lane];
        ax += w0 * bf2f(v0.x); ay += w0 * bf2f(v0.y);
        az += w0 * bf2f(v0.z); aw += w0 * bf2f(v0.w);
        bx += w1 * bf2f(v1q.x); by += w1 * bf2f(v1q.y);
        bz += w1 * bf2f(v1q.z); bw += w1 * bf2f(v1q.w);
    }
    if (j < p1) {
        int r0 = srow[j];
        float w0 = snorm[j];
        ushort4 v0 = h4[(size_t)r0 * 64 + lane];
        ax += w0 * bf2f(v0.x); ay += w0 * bf2f(v0.y);
        az += w0 * bf2f(v0.z); aw += w0 * bf2f(v0.w);
    }
    float ox = ax + bx, oy = ay + by, oz = az + bz, ow = aw + bw;
    if (dstb) {
        ushort4 o;
        o.x = f2bf(ox); o.y = f2bf(oy); o.z = f2bf(oz); o.w = f2bf(ow);
        ((ushort4*)dstb)[cbase] = o;
    } else {
        float s1c = s1[c], s2c = s2[c];
        float4 a1 = ((const float4*)v1)[lane];
        float4 a2 = ((const float4*)v2)[lane];
        float4 a3 = ((const float4*)b3)[lane];
        ox += s2c * a1.x + s1c * a2.x + a3.x;
        oy += s2c * a1.y + s1c * a2.y + a3.y;
        oz += s2c * a1.z + s1c * a2.z + a3.z;
        ow += s2c * a1.w + s1c * a2.w + a3.w;
        ((float4*)dstf)[cbase] = make_float4(ox, oy, oz, ow);
    }
}

// ----------------------------------------------------------------------
// Linearity collapse: no nonlinearity between GCN layers, so
//   out_t = A^3 · emb[ids] · (W1 W2 W3) + (A^2 1)⊗(b1 W2 W3) + (A 1)⊗(b2 W3) + 1⊗b3
// One GEMM (with fused embedding gather) + 3 sparse aggs per timestep.
extern "C" void kernel_launch(void* const* d_in, const int* in_sizes, int n_in,
                              void* d_out, int out_size, void* d_ws, size_t ws_size,
                              hipStream_t stream) {
    const int*   node_features = (const int*)d_in[0];   // [T, N]
    const int*   edge_index    = (const int*)d_in[1];   // [T, 2, E]
    const float* edge_weight   = (const float*)d_in[2]; // [T, E]
    const float* emb           = (const float*)d_in[3]; // [VOCAB, D]
    const float* W1 = (const float*)d_in[4];
    const float* b1 = (const float*)d_in[5];
    const float* W2 = (const float*)d_in[6];
    const float* b2 = (const float*)d_in[7];
    const float* W3 = (const float*)d_in[8];
    const float* b3 = (const float*)d_in[9];
    float* out = (float*)d_out;

    // workspace layout
    char* ws = (char*)d_ws;
    size_t off = 0;
    auto alloc = [&](size_t bytes) -> void* {
        void* p = ws + off;
        off = (off + bytes + 255) & ~(size_t)255;
        return p;
    };
    unsigned short* ebf    = (unsigned short*)alloc((size_t)VOCAB * DD * 2); // bf16 emb
    unsigned short* xb     = (unsigned short*)alloc((size_t)NN * DD * 2);    // bf16
    unsigned short* h2     = (unsigned short*)alloc((size_t)NN * DD * 2);    // bf16
    unsigned short* wtc    = (unsigned short*)alloc((size_t)DD * DD * 2);    // Wc^T bf16
    float* Wtmp   = (float*)alloc((size_t)DD * DD * 4);   // W1@W2
    float* Wc32   = (float*)alloc((size_t)DD * DD * 4);   // W1@W2@W3
    float* u      = (float*)alloc((size_t)DD * 4);        // b1@W2
    float* v1     = (float*)alloc((size_t)DD * 4);        // b1@W2@W3
    float* v2     = (float*)alloc((size_t)DD * 4);        // b2@W3
    float* deg    = (float*)alloc((size_t)NN * 4);
    float* dinv   = (float*)alloc((size_t)NN * 4);
    float* s1v    = (float*)alloc((size_t)NN * 4);
    float* s2v    = (float*)alloc((size_t)NN * 4);
    int*   cnt    = (int*)alloc((size_t)NN * 4);
    int*   colptr = (int*)alloc((size_t)(NN + 1) * 4);
    int*   next   = (int*)alloc((size_t)NN * 4);
    int*   srow   = (int*)alloc((size_t)EE * 4);
    float* snorm  = (float*)alloc((size_t)EE * 4);
    int*   bsum   = (int*)alloc((size_t)NB * 4);
    int*   boff   = (int*)alloc((size_t)NB * 4);
    (void)ws_size; (void)n_in; (void)in_sizes; (void)out_size;

    const int gN   = (NN + 255) / 256;   // == NB
    const int gE   = (EE + 255) / 256;
    const int gAgg = (NN + 3) / 4;
    const int gEmb = (VOCAB * 64 + 255) / 256;
    dim3 gGemm(2, (NN + 127) / 128);

    // ---- once per launch: collapsed weights, bias vectors, bf16 emb table
    convert_emb<<<gEmb, 256, 0, stream>>>(emb, ebf, VOCAB * 64);
    matmul256<<<256, 256, 0, stream>>>(W1, W2, Wtmp);
    matmul256<<<256, 256, 0, stream>>>(Wtmp, W3, Wc32);
    convert_wc<<<256, 256, 0, stream>>>(Wc32, wtc);
    matvec256<<<1, 256, 0, stream>>>(b1, W2, u);
    matvec256<<<1, 256, 0, stream>>>(u, W3, v1);
    matvec256<<<1, 256, 0, stream>>>(b2, W3, v2);

    for (int t = 0; t < T_STEPS; ++t) {
        const int*   ids = node_features + (size_t)t * NN;
        const int*   row = edge_index + (size_t)t * 2 * EE;
        const int*   col = row + EE;
        const float* w   = edge_weight + (size_t)t * EE;

        // per-timestep graph preprocessing (shared by all 3 aggs)
        init_deg_cnt<<<gN, 256, 0, stream>>>(deg, cnt, NN);
        edge_deg_cnt<<<gE, 256, 0, stream>>>(col, w, deg, cnt, EE);
        compute_dinv<<<gN, 256, 0, stream>>>(deg, dinv, NN);
        block_sums<<<NB, 256, 0, stream>>>(cnt, bsum, NN);
        scan_bsum<<<1, 256, 0, stream>>>(bsum, boff, NB);
        scan_final<<<NB, 256, 0, stream>>>(cnt, boff, colptr, next, NN, EE);
        fill_csr<<<gE, 256, 0, stream>>>(row, col, w, dinv, next, srow, snorm, EE);

        // bias propagation vectors: s1 = A·1, s2 = A·s1
        s1_kernel<<<gN, 256, 0, stream>>>(colptr, snorm, dinv, s1v, NN);
        s2_kernel<<<gN, 256, 0, stream>>>(colptr, srow, snorm, dinv, s1v, s2v, NN);

        // Z = emb[ids] @ Wc  (embedding gather fused into GEMM A-staging)
        mfma_gemm<<<gGemm, 256, 0, stream>>>(ids, ebf, wtc, h2, NN);

        // A·Z -> xb, A·(A·Z) -> h2, A·(A·A·Z) + bias terms -> out
        agg_kernel<<<gAgg, 256, 0, stream>>>(h2, colptr, srow, snorm, dinv,
                                             nullptr, nullptr, nullptr, nullptr, nullptr,
                                             nullptr, xb, NN);
        agg_kernel<<<gAgg, 256, 0, stream>>>(xb, colptr, srow, snorm, dinv,
                                             nullptr, nullptr, nullptr, nullptr, nullptr,
                                             nullptr, h2, NN);
        agg_kernel<<<gAgg, 256, 0, stream>>>(h2, colptr, srow, snorm, dinv,
                                             s1v, s2v, v1, v2, b3,
                                             out + (size_t)t * NN * DD, nullptr, NN);
    }
}

// Round 2
// 1796.560 us; speedup vs baseline: 1.0818x; 1.0006x over previous
//
#include <hip/hip_runtime.h>

// Problem constants (SpatialEncoding_46943992545790)
#define T_STEPS 4
#define NN 50000
#define EE 800000
#define DD 256
#define VOCAB 64000
#define NB ((NN + 255) / 256)   // 196 scan blocks

typedef __attribute__((ext_vector_type(8))) short short8;
typedef __attribute__((ext_vector_type(4))) float floatx4;

// ---------------------------------------------------------------- bf16 helpers
__device__ __forceinline__ unsigned short f2bf(float f) {
    unsigned u = __float_as_uint(f);
    return (unsigned short)((u + 0x7FFFu + ((u >> 16) & 1u)) >> 16);  // RNE
}
__device__ __forceinline__ float bf2f(unsigned short s) {
    return __uint_as_float(((unsigned)s) << 16);
}

__device__ __forceinline__ void async16(const unsigned short* g, unsigned short* l) {
    __builtin_amdgcn_global_load_lds(
        (const __attribute__((address_space(1))) void*)g,
        (__attribute__((address_space(3))) void*)l, 16, 0, 0);
}

// ---------------------------------------------------------------- init
__global__ __launch_bounds__(256) void init_deg_cnt(float* __restrict__ deg,
                                                    int* __restrict__ cnt, int n) {
    int i = blockIdx.x * 256 + threadIdx.x;
    if (i < n) { deg[i] = 1.0f; cnt[i] = 0; }   // self-loop weight 1
}

// ------------------------------------------------- edge pass: deg + counts
__global__ __launch_bounds__(256) void edge_deg_cnt(const int* __restrict__ col,
                                                    const float* __restrict__ w,
                                                    float* __restrict__ deg,
                                                    int* __restrict__ cnt, int e) {
    int i = blockIdx.x * 256 + threadIdx.x;
    if (i < e) {
        int c = col[i];
        atomicAdd(&deg[c], w[i]);
        atomicAdd(&cnt[c], 1);
    }
}

// ------------------------------- fused: dinv + s1 self-seed + scan pass 1
__global__ __launch_bounds__(256) void dinv_bsums(const float* __restrict__ deg,
                                                  float* __restrict__ dinv,
                                                  float* __restrict__ s1,
                                                  const int* __restrict__ cnt,
                                                  int* __restrict__ bsum, int n) {
    int i = blockIdx.x * 256 + threadIdx.x;
    if (i < n) {
        float d = deg[i];
        float r = d > 0.0f ? rsqrtf(d) : 0.0f;
        dinv[i] = r;
        s1[i] = r * r;            // self-loop contribution to s1 = A·1
    }
    __shared__ int sm[256];
    sm[threadIdx.x] = (i < n) ? cnt[i] : 0;
    __syncthreads();
    for (int s = 128; s > 0; s >>= 1) {
        if ((int)threadIdx.x < s) sm[threadIdx.x] += sm[threadIdx.x + s];
        __syncthreads();
    }
    if (threadIdx.x == 0) bsum[blockIdx.x] = sm[0];
}

// --------------------------------------------------- parallel scan, pass 2
__global__ __launch_bounds__(256) void scan_bsum(const int* __restrict__ bsum,
                                                 int* __restrict__ boff, int nb) {
    __shared__ int sm[256];
    int v = ((int)threadIdx.x < nb) ? bsum[threadIdx.x] : 0;
    sm[threadIdx.x] = v;
    __syncthreads();
    for (int o = 1; o < 256; o <<= 1) {
        int t = (threadIdx.x >= (unsigned)o) ? sm[threadIdx.x - o] : 0;
        __syncthreads();
        sm[threadIdx.x] += t;
        __syncthreads();
    }
    if ((int)threadIdx.x < nb) boff[threadIdx.x] = sm[threadIdx.x] - v;
}

// --------------------------------------------------- parallel scan, pass 3
__global__ __launch_bounds__(256) void scan_final(const int* __restrict__ cnt,
                                                  const int* __restrict__ boff,
                                                  int* __restrict__ colptr,
                                                  int* __restrict__ next, int n, int e) {
    __shared__ int sm[256];
    int i = blockIdx.x * 256 + threadIdx.x;
    int v = (i < n) ? cnt[i] : 0;
    sm[threadIdx.x] = v;
    __syncthreads();
    for (int o = 1; o < 256; o <<= 1) {
        int t = (threadIdx.x >= (unsigned)o) ? sm[threadIdx.x - o] : 0;
        __syncthreads();
        sm[threadIdx.x] += t;
        __syncthreads();
    }
    int excl = sm[threadIdx.x] - v + boff[blockIdx.x];
    if (i < n) { colptr[i] = excl; next[i] = excl; }
    if (i == 0) colptr[n] = e;   // every edge's col is in [0,n)
}

// --------------------------------------- fill CSR (packed edges) + s1 atomics
__global__ __launch_bounds__(256) void fill_csr(const int* __restrict__ row,
                                                const int* __restrict__ col,
                                                const float* __restrict__ w,
                                                const float* __restrict__ dinv,
                                                int* __restrict__ next,
                                                int2* __restrict__ edges,
                                                float* __restrict__ s1, int e) {
    int i = blockIdx.x * 256 + threadIdx.x;
    if (i < e) {
        int r = row[i], c = col[i];
        float nm = dinv[r] * w[i] * dinv[c];
        int p = atomicAdd(&next[c], 1);
        edges[p] = make_int2(r, __float_as_int(nm));
        atomicAdd(&s1[c], nm);     // completes s1 = A·1 (self seeded in dinv_bsums)
    }
}

// --------------------------------- fp32 256x256 matmul: C = A @ B (once/launch)
__global__ __launch_bounds__(256) void matmul256(const float* __restrict__ A,
                                                 const float* __restrict__ B,
                                                 float* __restrict__ C) {
    __shared__ float arow[256];
    int i = blockIdx.x, j = threadIdx.x;
    arow[j] = A[i * 256 + j];
    __syncthreads();
    float acc = 0.f;
#pragma unroll 8
    for (int k = 0; k < 256; ++k) acc += arow[k] * B[k * 256 + j];
    C[i * 256 + j] = acc;
}

// --------------------------------- fp32 matvec: y = x @ W  (1 block, once/launch)
__global__ __launch_bounds__(256) void matvec256(const float* __restrict__ x,
                                                 const float* __restrict__ W,
                                                 float* __restrict__ y) {
    __shared__ float xs[256];
    int j = threadIdx.x;
    xs[j] = x[j];
    __syncthreads();
    float acc = 0.f;
#pragma unroll 8
    for (int k = 0; k < 256; ++k) acc += xs[k] * W[k * 256 + j];
    y[j] = acc;
}

// --------------------------------- Wc[k][n] fp32 -> wt[n][k] bf16 (transposed)
__global__ __launch_bounds__(256) void convert_wc(const float* __restrict__ Wc,
                                                  unsigned short* __restrict__ wt) {
    int n = blockIdx.x;          // 0..255
    int k = threadIdx.x;         // 0..255
    wt[n * 256 + k] = f2bf(Wc[k * 256 + n]);
}

// --------------------------------- emb fp32 -> bf16 (once per launch)
__global__ __launch_bounds__(256) void convert_emb(const float* __restrict__ emb,
                                                   unsigned short* __restrict__ ebf,
                                                   int total4) {
    int t = blockIdx.x * 256 + threadIdx.x;
    if (t < total4) {
        float4 v = ((const float4*)emb)[t];
        ushort4 o;
        o.x = f2bf(v.x); o.y = f2bf(v.y); o.z = f2bf(v.z); o.w = f2bf(v.w);
        ((ushort4*)ebf)[t] = o;
    }
}

// ------------------------------------------------------- bf16 MFMA GEMM + gather
// h2[M,256](bf16) = ebf[ids[M],256](bf16) @ W, wt = W^T (bf16 [n][k]).
// BM=128, BN=256 (full width: A gathered once), BK=32, 4 waves; wave = 64x128
// via 4x8 grid of 16x16x32 MFMA tiles. LDS chunk-column-major (chunk = 8 bf16).
__global__ __launch_bounds__(256) void mfma_gemm(const int* __restrict__ ids,
                                                 const unsigned short* __restrict__ ebf,
                                                 const unsigned short* __restrict__ wt,
                                                 unsigned short* __restrict__ h2,
                                                 int M) {
    __shared__ __align__(16) unsigned short As[128 * 32];   // 8 KB
    __shared__ __align__(16) unsigned short Bs[256 * 32];   // 16 KB

    int tid = threadIdx.x;
    int lane = tid & 63;
    int wave = tid >> 6;
    int row0 = blockIdx.x * 128;
    int wm = (wave & 1) * 64;
    int wn = (wave >> 1) * 128;
    int quad = lane >> 4;
    int cl = lane & 15;

    // A staging: 2 units/thread, u = s*256+tid; c = u>>7 (k-chunk), m = u&127
    int uA0 = tid, uA1 = 256 + tid;
    int cA0 = uA0 >> 7, mA0 = uA0 & 127;
    int cA1 = uA1 >> 7;                       // same row (uA1&127 == mA0)
    int gr = row0 + mA0; if (gr >= M) gr = M - 1;
    int id0 = ids[gr];                        // embedding gather index
    const unsigned short* srcA0 = ebf + (size_t)id0 * 256 + cA0 * 8;
    const unsigned short* srcA1 = ebf + (size_t)id0 * 256 + cA1 * 8;
    unsigned short* dstA0 = As + uA0 * 8;
    unsigned short* dstA1 = As + uA1 * 8;

    // B staging: 4 units/thread, unit s: chunk=s, n=tid
    const unsigned short* srcB = wt + (size_t)tid * 256;
    unsigned short* dstBbase = Bs + tid * 8;

    floatx4 acc[4][8] = {};

    for (int k0 = 0; k0 < 256; k0 += 32) {
        if (k0) __syncthreads();          // protect LDS from prior reads
        async16(srcA0 + k0, dstA0);
        async16(srcA1 + k0, dstA1);
#pragma unroll
        for (int s5 = 0; s5 < 4; ++s5)
            async16(srcB + s5 * 8 + k0, dstBbase + s5 * 2048);
        __syncthreads();                  // drains vmcnt before barrier

        short8 af[4], bfr[8];
#pragma unroll
        for (int i = 0; i < 4; ++i)
            af[i] = *(const short8*)&As[(quad * 128 + wm + i * 16 + cl) * 8];
#pragma unroll
        for (int j = 0; j < 8; ++j)
            bfr[j] = *(const short8*)&Bs[(quad * 256 + wn + j * 16 + cl) * 8];
#pragma unroll
        for (int i = 0; i < 4; ++i)
#pragma unroll
            for (int j = 0; j < 8; ++j)
                acc[i][j] = __builtin_amdgcn_mfma_f32_16x16x32_bf16(
                    af[i], bfr[j], acc[i][j], 0, 0, 0);
    }

    // epilogue: D[row=quad*4+reg][col=lane&15] per 16x16 tile
#pragma unroll
    for (int i = 0; i < 4; ++i) {
#pragma unroll
        for (int r = 0; r < 4; ++r) {
            int gr2 = row0 + wm + i * 16 + quad * 4 + r;
            if (gr2 < M) {
                size_t base = (size_t)gr2 * 256 + wn + cl;
#pragma unroll
                for (int j = 0; j < 8; ++j)
                    h2[base + j * 16] = f2bf(acc[i][j][r]);
            }
        }
    }
}

// ------------------------------------------- CSR aggregate (bf16 gather)
// One dest row per wave; halves (lanes 0-31 / 32-63) process even/odd edges,
// each lane loads 16 B (ushort8) so 32 lanes cover the 512 B row. Unroll x2
// -> 4 edges, 2 KB in flight per iteration. Halves combined via shfl(lane^32).
// agg1: also computes s2[c] = self*s1[c] + sum(norm * s1[srow]).
// final: adds s2[c]*v1 + s1[c]*v2 + b3, writes fp32.
__global__ __launch_bounds__(256) void agg_kernel(const unsigned short* __restrict__ h2,
                                                  const int* __restrict__ colptr,
                                                  const int2* __restrict__ edges,
                                                  const float* __restrict__ dinv,
                                                  const float* __restrict__ s1,
                                                  float* __restrict__ s2_out,
                                                  const float* __restrict__ s2,
                                                  const float* __restrict__ v1,
                                                  const float* __restrict__ v2,
                                                  const float* __restrict__ b3,
                                                  float* __restrict__ dstf,
                                                  unsigned short* __restrict__ dstb,
                                                  int n) {
    int wave = threadIdx.x >> 6;
    int lane = threadIdx.x & 63;
    int h = lane >> 5;          // which edge of the pair
    int s = lane & 31;          // feature sublane: features s*8 .. s*8+7
    int c = blockIdx.x * 4 + wave;
    if (c >= n) return;
    int p0 = colptr[c];
    int p1 = colptr[c + 1];
    float di = dinv[c];
    float self = di * di;
    bool do_s2 = (s2_out != nullptr);

    float accA[8] = {}, accB[8] = {};
    float ssA = 0.f, ssB = 0.f;

    if (h == 0) {   // self-loop term on half 0 only
        short8 v = *(const short8*)(h2 + (size_t)c * 256 + s * 8);
#pragma unroll
        for (int k = 0; k < 8; ++k) accA[k] += self * bf2f((unsigned short)v[k]);
    }

    int j = p0 + h;             // this half's edge stream: j, j+2, j+4, ...
    for (; j + 2 < p1; j += 4) {
        int2 e0 = edges[j];
        int2 e1 = edges[j + 2];
        float w0 = __int_as_float(e0.y);
        float w1 = __int_as_float(e1.y);
        short8 va = *(const short8*)(h2 + (size_t)e0.x * 256 + s * 8);
        short8 vb = *(const short8*)(h2 + (size_t)e1.x * 256 + s * 8);
        if (do_s2) { ssA += w0 * s1[e0.x]; ssB += w1 * s1[e1.x]; }
#pragma unroll
        for (int k = 0; k < 8; ++k) {
            accA[k] += w0 * bf2f((unsigned short)va[k]);
            accB[k] += w1 * bf2f((unsigned short)vb[k]);
        }
    }
    if (j < p1) {               // at most one edge left per half
        int2 e0 = edges[j];
        float w0 = __int_as_float(e0.y);
        short8 va = *(const short8*)(h2 + (size_t)e0.x * 256 + s * 8);
        if (do_s2) ssA += w0 * s1[e0.x];
#pragma unroll
        for (int k = 0; k < 8; ++k) accA[k] += w0 * bf2f((unsigned short)va[k]);
    }

    // combine halves
    float tot[8];
#pragma unroll
    for (int k = 0; k < 8; ++k) {
        float o = accA[k] + accB[k];
        tot[k] = o + __shfl(o, lane ^ 32, 64);
    }
    if (do_s2) {
        float ss = ssA + ssB;
        ss += __shfl(ss, lane ^ 32, 64);
        if (lane == 0) s2_out[c] = self * s1[c] + ss;
    }

    if (dstb) {
        if (h == 0) {
            short8 o;
#pragma unroll
            for (int k = 0; k < 8; ++k) o[k] = (short)f2bf(tot[k]);
            *(short8*)(dstb + (size_t)c * 256 + s * 8) = o;
        }
    } else {
        if (h == 0) {
            float s1c = s1[c], s2c = s2[c];
            int f0 = s * 8;
            float ob[8];
#pragma unroll
            for (int k = 0; k < 8; ++k)
                ob[k] = tot[k] + s2c * v1[f0 + k] + s1c * v2[f0 + k] + b3[f0 + k];
            float* o = dstf + (size_t)c * 256 + f0;
            ((float4*)o)[0] = make_float4(ob[0], ob[1], ob[2], ob[3]);
            ((float4*)o)[1] = make_float4(ob[4], ob[5], ob[6], ob[7]);
        }
    }
}

// ----------------------------------------------------------------------
// Linearity collapse: no nonlinearity between GCN layers, so
//   out_t = A^3 · emb[ids] · (W1 W2 W3) + (A^2 1)⊗(b1 W2 W3) + (A 1)⊗(b2 W3) + 1⊗b3
// One GEMM (embedding gather fused into A-staging) + 3 sparse aggs per timestep.
extern "C" void kernel_launch(void* const* d_in, const int* in_sizes, int n_in,
                              void* d_out, int out_size, void* d_ws, size_t ws_size,
                              hipStream_t stream) {
    const int*   node_features = (const int*)d_in[0];   // [T, N]
    const int*   edge_index    = (const int*)d_in[1];   // [T, 2, E]
    const float* edge_weight   = (const float*)d_in[2]; // [T, E]
    const float* emb           = (const float*)d_in[3]; // [VOCAB, D]
    const float* W1 = (const float*)d_in[4];
    const float* b1 = (const float*)d_in[5];
    const float* W2 = (const float*)d_in[6];
    const float* b2 = (const float*)d_in[7];
    const float* W3 = (const float*)d_in[8];
    const float* b3 = (const float*)d_in[9];
    float* out = (float*)d_out;

    // workspace layout
    char* ws = (char*)d_ws;
    size_t off = 0;
    auto alloc = [&](size_t bytes) -> void* {
        void* p = ws + off;
        off = (off + bytes + 255) & ~(size_t)255;
        return p;
    };
    unsigned short* ebf    = (unsigned short*)alloc((size_t)VOCAB * DD * 2); // bf16 emb
    unsigned short* xb     = (unsigned short*)alloc((size_t)NN * DD * 2);    // bf16
    unsigned short* h2     = (unsigned short*)alloc((size_t)NN * DD * 2);    // bf16
    unsigned short* wtc    = (unsigned short*)alloc((size_t)DD * DD * 2);    // Wc^T bf16
    float* Wtmp   = (float*)alloc((size_t)DD * DD * 4);   // W1@W2
    float* Wc32   = (float*)alloc((size_t)DD * DD * 4);   // W1@W2@W3
    float* u      = (float*)alloc((size_t)DD * 4);        // b1@W2
    float* v1     = (float*)alloc((size_t)DD * 4);        // b1@W2@W3
    float* v2     = (float*)alloc((size_t)DD * 4);        // b2@W3
    float* deg    = (float*)alloc((size_t)NN * 4);
    float* dinv   = (float*)alloc((size_t)NN * 4);
    float* s1v    = (float*)alloc((size_t)NN * 4);
    float* s2v    = (float*)alloc((size_t)NN * 4);
    int*   cnt    = (int*)alloc((size_t)NN * 4);
    int*   colptr = (int*)alloc((size_t)(NN + 1) * 4);
    int*   next   = (int*)alloc((size_t)NN * 4);
    int2*  edges  = (int2*)alloc((size_t)EE * 8);
    int*   bsum   = (int*)alloc((size_t)NB * 4);
    int*   boff   = (int*)alloc((size_t)NB * 4);
    (void)ws_size; (void)n_in; (void)in_sizes; (void)out_size;

    const int gN   = (NN + 255) / 256;   // == NB
    const int gE   = (EE + 255) / 256;
    const int gAgg = (NN + 3) / 4;
    const int gEmb = (VOCAB * 64 + 255) / 256;
    const int gGemm = (NN + 127) / 128;

    // ---- once per launch: collapsed weights, bias vectors, bf16 emb table
    convert_emb<<<gEmb, 256, 0, stream>>>(emb, ebf, VOCAB * 64);
    matmul256<<<256, 256, 0, stream>>>(W1, W2, Wtmp);
    matmul256<<<256, 256, 0, stream>>>(Wtmp, W3, Wc32);
    convert_wc<<<256, 256, 0, stream>>>(Wc32, wtc);
    matvec256<<<1, 256, 0, stream>>>(b1, W2, u);
    matvec256<<<1, 256, 0, stream>>>(u, W3, v1);
    matvec256<<<1, 256, 0, stream>>>(b2, W3, v2);

    for (int t = 0; t < T_STEPS; ++t) {
        const int*   ids = node_features + (size_t)t * NN;
        const int*   row = edge_index + (size_t)t * 2 * EE;
        const int*   col = row + EE;
        const float* w   = edge_weight + (size_t)t * EE;

        // per-timestep graph preprocessing (shared by all 3 aggs)
        init_deg_cnt<<<gN, 256, 0, stream>>>(deg, cnt, NN);
        edge_deg_cnt<<<gE, 256, 0, stream>>>(col, w, deg, cnt, EE);
        dinv_bsums<<<gN, 256, 0, stream>>>(deg, dinv, s1v, cnt, bsum, NN);
        scan_bsum<<<1, 256, 0, stream>>>(bsum, boff, NB);
        scan_final<<<gN, 256, 0, stream>>>(cnt, boff, colptr, next, NN, EE);
        fill_csr<<<gE, 256, 0, stream>>>(row, col, w, dinv, next, edges, s1v, EE);

        // Z = emb[ids] @ Wc  (embedding gather fused into GEMM A-staging)
        mfma_gemm<<<gGemm, 256, 0, stream>>>(ids, ebf, wtc, h2, NN);

        // A·Z -> xb (also s2 = A·s1), A·(A·Z) -> h2, A·(A·A·Z) + bias -> out
        agg_kernel<<<gAgg, 256, 0, stream>>>(h2, colptr, edges, dinv,
                                             s1v, s2v, nullptr, nullptr, nullptr, nullptr,
                                             nullptr, xb, NN);
        agg_kernel<<<gAgg, 256, 0, stream>>>(xb, colptr, edges, dinv,
                                             nullptr, nullptr, nullptr, nullptr, nullptr, nullptr,
                                             nullptr, h2, NN);
        agg_kernel<<<gAgg, 256, 0, stream>>>(h2, colptr, edges, dinv,
                                             s1v, nullptr, s2v, v1, v2, b3,
                                             out + (size_t)t * NN * DD, nullptr, NN);
    }
}